// Round 1
// 855.538 us; speedup vs baseline: 1.1382x; 1.1382x over previous
//
#include <hip/hip_runtime.h>
#include <cstdint>
#include <cstddef>

#define BSZ 16
#define T   8192
#define CDIM 256
#define HDIM 256
#define KW  7

constexpr int BT = BSZ * T;                  // 131072
constexpr float TAU = 2e-3f;                 // f64 recheck band for |d| (fp16 path: sigma_d ~1.5e-4, band ~13 sigma)
constexpr int UCAP = 32768;

typedef __attribute__((ext_vector_type(8))) short short8;
typedef _Float16 half8 __attribute__((ext_vector_type(8)));
typedef __attribute__((ext_vector_type(4))) float f32x4;

// ---------------- workspace layout (byte offsets, all 16B-aligned) ----------------
constexpr size_t B_W1T  = 0;                         // f32 [7][256][256]  1835008 B (exact copy, for f64 recheck)
constexpr size_t B_W2T  = B_W1T + 1835008;           // f32 [3][256][256]   786432 B
constexpr size_t B_V    = B_W2T + 786432;            // f32 [256]
constexpr size_t B_D    = B_V + 1024;                // f32 [BT]
constexpr size_t B_ISB  = B_D + 524288;              // i32 [BT]
constexpr size_t B_SID  = B_ISB + 524288;            // i32 [BT]
constexpr size_t B_SST  = B_SID + 524288;            // i32 [BT]
constexpr size_t B_SEN  = B_SST + 524288;            // i32 [BT]
constexpr size_t B_NV   = B_SEN + 524288;            // i32 [16]
constexpr size_t B_UCT  = B_NV + 64;                 // i32 [1]
constexpr size_t B_UL   = B_UCT + 16;                // i32 [UCAP]
constexpr size_t B_ZERO = B_UL + 131072;             // 256 B of zeros (DMA clamp target)
constexpr size_t B_W1B  = B_ZERO + 256;              // f16 [256][1792]    917504 B
constexpr size_t B_W2B  = B_W1B + 917504;            // f16 [256][768]     393216 B  -> ~6.0 MB total

// async global->LDS, 16B per lane; LDS dest = wave-uniform base + lane*16 (global addr per-lane)
__device__ __forceinline__ void gl_lds16(const void* g, void* l) {
    __builtin_amdgcn_global_load_lds(
        (const __attribute__((address_space(1))) unsigned int*)g,
        (__attribute__((address_space(3))) unsigned int*)l,
        16, 0, 0);
}

// f32 -> f16 RNE (hardware default round mode for v_cvt_f16_f32)
__device__ __forceinline__ unsigned short f16_rne(float f) {
    _Float16 h = (_Float16)f;
    return __builtin_bit_cast(unsigned short, h);
}

// ---------------- weight repack ----------------
// W1T[k][c][h] f32 (recheck); W1b[h][kw*256+c] f16 RNE; same for w2; v[h]=w3[1,h]-w3[0,h]
__global__ void repack_kernel(const float* __restrict__ w1, const float* __restrict__ w2,
                              const float* __restrict__ w3,
                              float* __restrict__ W1T, float* __restrict__ W2T,
                              float* __restrict__ v,
                              unsigned short* __restrict__ W1b, unsigned short* __restrict__ W2b)
{
    int idx = blockIdx.x * blockDim.x + threadIdx.x;
    int stride = gridDim.x * blockDim.x;
    for (int i = idx; i < KW * CDIM * HDIM; i += stride) {
        int k = i / (CDIM * HDIM), c = (i / HDIM) % CDIM, h = i % HDIM;
        W1T[i] = w1[(size_t)h * (CDIM * KW) + c * KW + k];
    }
    for (int i = idx; i < 3 * HDIM * HDIM; i += stride) {
        int k = i / (HDIM * HDIM), c = (i / HDIM) % HDIM, h = i % HDIM;
        W2T[i] = w2[(size_t)h * (HDIM * 3) + c * 3 + k];
    }
    for (int i = idx; i < HDIM * 1792; i += stride) {
        int h = i / 1792, kc = i % 1792, kw = kc >> 8, c = kc & 255;
        W1b[i] = f16_rne(w1[(size_t)h * 1792 + c * 7 + kw]);
    }
    for (int i = idx; i < HDIM * 768; i += stride) {
        int h = i / 768, kc = i % 768, kw = kc >> 8, c = kc & 255;
        W2b[i] = f16_rne(w2[(size_t)h * 768 + c * 3 + kw]);
    }
    if (idx < HDIM) v[idx] = w3[HDIM + idx] - w3[idx];
}

// ---------------- x -> f16 (RNE) one-time cast ----------------
__global__ __launch_bounds__(256) void xcast_kernel(const float* __restrict__ x,
                                                    unsigned short* __restrict__ xhf)
{
    size_t i = ((size_t)blockIdx.x * 256 + threadIdx.x) * 8;
    float4 a = *(const float4*)(x + i);
    float4 b = *(const float4*)(x + i + 4);
    short8 o;
    o[0] = (short)f16_rne(a.x); o[1] = (short)f16_rne(a.y);
    o[2] = (short)f16_rne(a.z); o[3] = (short)f16_rne(a.w);
    o[4] = (short)f16_rne(b.x); o[5] = (short)f16_rne(b.y);
    o[6] = (short)f16_rne(b.z); o[7] = (short)f16_rne(b.w);
    *(short8*)(xhf + i) = o;
}

// ---------------- conv1: pure f16 MFMA, all-DMA staging ----------------
// Block 256t x 128h, 4 waves of 64t x 128h. cc-chunks of 32 c; B staged 4 kw taps
// per phase (4 barriers/cc). A rows padded to stride 322 (322%8=2 -> bank spread),
// B n-stride 130 (130%8=2).
__global__ __launch_bounds__(256) void conv1_mfma(
    const unsigned short* __restrict__ xhf,
    const unsigned short* __restrict__ Wb,
    const float* __restrict__ b1,
    const unsigned short* __restrict__ zerobuf,
    unsigned short* __restrict__ h1)
{
    __shared__ half8 A8[4 * 322];        // [q][row], rows 0..261 valid (t = t0+row-3)
    __shared__ half8 B8[16 * 130];       // [kwslot][q][n]
    const int tid = threadIdx.x, lane = tid & 63, wid = tid >> 6;
    const int b  = blockIdx.x >> 5;
    const int t0 = (blockIdx.x & 31) << 8;
    const int h0 = blockIdx.y << 7;
    const int q = lane >> 4, l15 = lane & 15;
    const unsigned short* xb = xhf + (size_t)b * T * 256;

    f32x4 acc[4][8] = {};

    for (int cc = 0; cc < 8; ++cc) {
        const int c0 = cc << 5;
        __syncthreads();
        // A: 20 segs; wave wid handles q=wid, parts 0..4
        #pragma unroll
        for (int part = 0; part < 5; ++part) {
            int row = part * 64 + lane;
            int t = t0 + row - 3;
            const unsigned short* src = (row < 262 && t >= 0 && t < T)
                ? xb + (size_t)t * 256 + c0 + wid * 8 : zerobuf;
            gl_lds16(src, &A8[wid * 322 + part * 64]);
        }
        // B kw 0..3: wave wid stages kw=wid (8 segs: 4 q x 2 halves)
        #pragma unroll
        for (int s = 0; s < 8; ++s) {
            int bq = s >> 1, half = s & 1;
            const unsigned short* src = Wb + (size_t)(h0 + half * 64 + lane) * 1792
                                        + wid * 256 + c0 + bq * 8;
            gl_lds16(src, &B8[(wid * 4 + bq) * 130 + half * 64]);
        }
        __syncthreads();
        #pragma unroll
        for (int kw = 0; kw < 4; ++kw) {
            half8 ah[4], bh[8];
            const int rbase = wid * 64 + l15 + kw;
            #pragma unroll
            for (int i = 0; i < 4; ++i) ah[i] = A8[q * 322 + rbase + i * 16];
            #pragma unroll
            for (int j = 0; j < 8; ++j) bh[j] = B8[(kw * 4 + q) * 130 + j * 16 + l15];
            #pragma unroll
            for (int i = 0; i < 4; ++i)
                #pragma unroll
                for (int j = 0; j < 8; ++j)
                    acc[i][j] = __builtin_amdgcn_mfma_f32_16x16x32_f16(ah[i], bh[j], acc[i][j], 0, 0, 0);
        }
        __syncthreads();
        // B kw 4..6: 24 segs, wave does 6
        #pragma unroll
        for (int s = 0; s < 6; ++s) {
            int seg = wid * 6 + s;
            int kw2 = seg >> 3, bq = (seg >> 1) & 3, half = seg & 1;
            const unsigned short* src = Wb + (size_t)(h0 + half * 64 + lane) * 1792
                                        + (kw2 + 4) * 256 + c0 + bq * 8;
            gl_lds16(src, &B8[(kw2 * 4 + bq) * 130 + half * 64]);
        }
        __syncthreads();
        #pragma unroll
        for (int kw = 4; kw < 7; ++kw) {
            half8 ah[4], bh[8];
            const int rbase = wid * 64 + l15 + kw;
            const int slot = kw - 4;
            #pragma unroll
            for (int i = 0; i < 4; ++i) ah[i] = A8[q * 322 + rbase + i * 16];
            #pragma unroll
            for (int j = 0; j < 8; ++j) bh[j] = B8[(slot * 4 + q) * 130 + j * 16 + l15];
            #pragma unroll
            for (int i = 0; i < 4; ++i)
                #pragma unroll
                for (int j = 0; j < 8; ++j)
                    acc[i][j] = __builtin_amdgcn_mfma_f32_16x16x32_f16(ah[i], bh[j], acc[i][j], 0, 0, 0);
        }
    }
    // epilogue: bias+relu, store h1 f16
    #pragma unroll
    for (int j = 0; j < 8; ++j) {
        int h = h0 + j * 16 + l15;
        float bb = b1[h];
        #pragma unroll
        for (int i = 0; i < 4; ++i) {
            int tb = t0 + wid * 64 + i * 16 + q * 4;
            #pragma unroll
            for (int r = 0; r < 4; ++r)
                h1[(size_t)(b * T + tb + r) * 256 + h] = f16_rne(fmaxf(acc[i][j][r] + bb, 0.f));
        }
    }
}

// ---------------- conv2: pure f16 MFMA + fused 1x1 score ----------------
__global__ __launch_bounds__(256) void conv2_mfma(
    const unsigned short* __restrict__ h1,
    const unsigned short* __restrict__ Wb,
    const float* __restrict__ b2, const float* __restrict__ v,
    const unsigned short* __restrict__ zerobuf,
    float* __restrict__ dlog)
{
    __shared__ half8 A8[4 * 322];        // rows 0..257 valid (t = t0+row-1)
    __shared__ half8 B8[12 * 130];       // 3 kw x 4 q x 130
    const int tid = threadIdx.x, lane = tid & 63, wid = tid >> 6;
    const int b  = blockIdx.x >> 5;
    const int t0 = (blockIdx.x & 31) << 8;
    const int h0 = blockIdx.y << 7;
    const int q = lane >> 4, l15 = lane & 15;
    const unsigned short* hb = h1 + (size_t)b * T * 256;

    f32x4 acc[4][8] = {};

    for (int cc = 0; cc < 8; ++cc) {
        const int c0 = cc << 5;
        __syncthreads();
        #pragma unroll
        for (int part = 0; part < 5; ++part) {
            int row = part * 64 + lane;
            int t = t0 + row - 1;
            const unsigned short* src = (row < 258 && t >= 0 && t < T)
                ? hb + (size_t)t * 256 + c0 + wid * 8 : zerobuf;
            gl_lds16(src, &A8[wid * 322 + part * 64]);
        }
        #pragma unroll
        for (int s = 0; s < 6; ++s) {
            int seg = wid * 6 + s;
            int kw = seg >> 3, bq = (seg >> 1) & 3, half = seg & 1;
            const unsigned short* src = Wb + (size_t)(h0 + half * 64 + lane) * 768
                                        + kw * 256 + c0 + bq * 8;
            gl_lds16(src, &B8[(kw * 4 + bq) * 130 + half * 64]);
        }
        __syncthreads();
        #pragma unroll
        for (int kw = 0; kw < 3; ++kw) {
            half8 ah[4], bh[8];
            const int rbase = wid * 64 + l15 + kw;
            #pragma unroll
            for (int i = 0; i < 4; ++i) ah[i] = A8[q * 322 + rbase + i * 16];
            #pragma unroll
            for (int j = 0; j < 8; ++j) bh[j] = B8[(kw * 4 + q) * 130 + j * 16 + l15];
            #pragma unroll
            for (int i = 0; i < 4; ++i)
                #pragma unroll
                for (int j = 0; j < 8; ++j)
                    acc[i][j] = __builtin_amdgcn_mfma_f32_16x16x32_f16(ah[i], bh[j], acc[i][j], 0, 0, 0);
        }
    }
    // epilogue: p = sum_h v[h]*relu(h2+b2), reduce 16 lanes per quad, atomicAdd per token
    float vv[8], bb[8];
    #pragma unroll
    for (int j = 0; j < 8; ++j) {
        int h = h0 + j * 16 + l15;
        vv[j] = v[h]; bb[j] = b2[h];
    }
    #pragma unroll
    for (int i = 0; i < 4; ++i) {
        int tb = t0 + wid * 64 + i * 16 + q * 4;
        #pragma unroll
        for (int r = 0; r < 4; ++r) {
            float s = 0.f;
            #pragma unroll
            for (int j = 0; j < 8; ++j)
                s += fmaxf(acc[i][j][r] + bb[j], 0.f) * vv[j];
            #pragma unroll
            for (int m = 1; m < 16; m <<= 1)
                s += __shfl_xor(s, m, 64);
            if (l15 == 0) atomicAdd(&dlog[b * T + tb + r], s);
        }
    }
}

// ---------------- boundary bit + uncertainty list ----------------
__global__ void boundary_kernel(const float* __restrict__ d, const int* __restrict__ padmask,
                                const float* __restrict__ b3,
                                int* __restrict__ isb, int* __restrict__ ucount,
                                int* __restrict__ ulist)
{
    int bt = blockIdx.x * 256 + threadIdx.x;
    if (bt >= BT) return;
    int pad = padmask[bt];
    float dd = d[bt] + (b3[1] - b3[0]);
    isb[bt] = (pad == 0 && dd > 0.f) ? 1 : 0;
    if (pad == 0 && fabsf(dd) < TAU) {
        int slot = atomicAdd(ucount, 1);
        if (slot < UCAP) ulist[slot] = bt;
    }
}

// ---------------- exact f64 recheck of near-tie tokens ----------------
__global__ __launch_bounds__(256) void recheck_kernel(
    const float* __restrict__ x, const float* __restrict__ W1T,
    const float* __restrict__ W2T, const float* __restrict__ b1,
    const float* __restrict__ b2, const float* __restrict__ w3,
    const float* __restrict__ b3,
    const int* __restrict__ ulist, const int* __restrict__ ucount,
    int* __restrict__ isb)
{
    __shared__ double h1s[3][HDIM];
    __shared__ double red[HDIM];
    int n = *ucount; if (n > UCAP) n = UCAP;
    const int h = threadIdx.x;
    for (int li = blockIdx.x; li < n; li += gridDim.x) {
        int bt = ulist[li];
        int b = bt >> 13, t = bt & (T - 1);
        #pragma unroll
        for (int dt = -1; dt <= 1; ++dt) {
            double acc = (double)b1[h];
            int tc = t + dt;
            if (tc >= 0 && tc < T) {
                for (int k = 0; k < KW; ++k) {
                    int tt = tc + k - 3;
                    if (tt < 0 || tt >= T) continue;
                    const float* xrow = &x[(size_t)(b * T + tt) * CDIM];
                    const float* wrow = &W1T[(size_t)k * 65536 + h];
                    for (int c = 0; c < CDIM; ++c)
                        acc += (double)xrow[c] * (double)wrow[(size_t)c * 256];
                }
            }
            h1s[dt + 1][h] = acc > 0.0 ? acc : 0.0;
        }
        __syncthreads();
        double acc2 = (double)b2[h];
        for (int k = 0; k < 3; ++k) {
            int tt = t + k - 1;
            if (tt < 0 || tt >= T) continue;
            const double* hrow = h1s[k];
            const float* wrow = &W2T[(size_t)k * 65536 + h];
            for (int c = 0; c < HDIM; ++c)
                acc2 += hrow[c] * (double)wrow[(size_t)c * 256];
        }
        double h2v = acc2 > 0.0 ? acc2 : 0.0;
        double vd = (double)w3[HDIM + h] - (double)w3[h];
        red[h] = vd * h2v;
        __syncthreads();
        for (int off = 128; off > 0; off >>= 1) {
            if (h < off) red[h] += red[h + off];
            __syncthreads();
        }
        if (h == 0) {
            double dd = red[0] + ((double)b3[1] - (double)b3[0]);
            isb[bt] = (dd > 0.0) ? 1 : 0;
        }
        __syncthreads();
    }
}

// ---------------- per-batch inclusive cumsum -> seg_id, n_valid ----------------
__global__ __launch_bounds__(1024) void scan_kernel(
    const int* __restrict__ isb, const int* __restrict__ padmask,
    int* __restrict__ sid, int* __restrict__ nvalid)
{
    __shared__ int ssum[1024];
    const int b = blockIdx.x, tid = threadIdx.x;
    const int base = b * T;
    int vals[8]; int s = 0;
    #pragma unroll
    for (int i = 0; i < 8; ++i) { vals[i] = isb[base + tid * 8 + i]; s += vals[i]; }
    ssum[tid] = s;
    __syncthreads();
    for (int off = 1; off < 1024; off <<= 1) {
        int add = (tid >= off) ? ssum[tid - off] : 0;
        __syncthreads();
        ssum[tid] += add;
        __syncthreads();
    }
    int run = ssum[tid] - s;
    #pragma unroll
    for (int i = 0; i < 8; ++i) {
        int t = tid * 8 + i;
        run += vals[i];
        sid[base + t] = (padmask[base + t] != 0) ? T : run;
    }
    if (tid == 1023) {
        int nb = ssum[1023];
        nvalid[b] = (padmask[base] == 0) ? (nb + 1) : 0;
    }
}

// ---------------- segment range extraction ----------------
__global__ void segbounds_kernel(const int* __restrict__ sid, const int* __restrict__ padmask,
                                 int* __restrict__ sst, int* __restrict__ sen)
{
    int bt = blockIdx.x * 256 + threadIdx.x;
    if (bt >= BT) return;
    if (padmask[bt] != 0) return;
    int t = bt & (T - 1);
    int b = bt >> 13;
    int s = sid[bt];
    if (t == 0) {
        if (s < T) sst[b * T + s] = 0;
    } else if (s != sid[bt - 1]) {
        if (s < T) sst[b * T + s] = t;
    }
    bool last = (t == T - 1) || (padmask[bt + 1] != 0);
    if (s < T && (last || sid[bt + 1] != s)) sen[b * T + s] = t + 1;
}

// ---------------- segment-mean pooling + new_pad ----------------
__global__ __launch_bounds__(256) void pool_kernel(
    const float* __restrict__ x, const int* __restrict__ sst,
    const int* __restrict__ sen, const int* __restrict__ nvalid,
    float* __restrict__ out)
{
    int slot = blockIdx.x * 4 + (threadIdx.x >> 6);
    int lane = threadIdx.x & 63;
    int b = slot >> 13;
    int s = slot & (T - 1);
    int nv = nvalid[b];
    float4 res = make_float4(0.f, 0.f, 0.f, 0.f);
    if (s < nv) {
        int st = sst[slot], en = sen[slot];
        if (st >= 0 && en > st) {
            float4 a = make_float4(0.f, 0.f, 0.f, 0.f);
            const float* xp = &x[(size_t)(b * T + st) * CDIM + lane * 4];
            for (int t = st; t < en; ++t) {
                float4 xv = *(const float4*)xp;
                a.x += xv.x; a.y += xv.y; a.z += xv.z; a.w += xv.w;
                xp += CDIM;
            }
            float inv = 1.f / (float)(en - st);
            res = make_float4(a.x * inv, a.y * inv, a.z * inv, a.w * inv);
        }
    }
    *(float4*)&out[(size_t)slot * CDIM + lane * 4] = res;
    if (lane == 0) out[(size_t)BT * CDIM + slot] = (s < nv) ? 0.f : 1.f;
}

extern "C" void kernel_launch(void* const* d_in, const int* in_sizes, int n_in,
                              void* d_out, int out_size, void* d_ws, size_t ws_size,
                              hipStream_t stream)
{
    const float* x  = (const float*)d_in[0];
    const int* padmask = (const int*)d_in[1];
    const float* w1 = (const float*)d_in[2];
    const float* b1 = (const float*)d_in[3];
    const float* w2 = (const float*)d_in[4];
    const float* b2 = (const float*)d_in[5];
    const float* w3 = (const float*)d_in[6];
    const float* b3 = (const float*)d_in[7];

    char* ws = (char*)d_ws;
    float* W1T = (float*)(ws + B_W1T);
    float* W2T = (float*)(ws + B_W2T);
    float* v   = (float*)(ws + B_V);
    float* dlog = (float*)(ws + B_D);
    int* isb = (int*)(ws + B_ISB);
    int* sid = (int*)(ws + B_SID);
    int* sst = (int*)(ws + B_SST);
    int* sen = (int*)(ws + B_SEN);
    int* nv  = (int*)(ws + B_NV);
    int* uct = (int*)(ws + B_UCT);
    int* ul  = (int*)(ws + B_UL);
    unsigned short* zerobuf = (unsigned short*)(ws + B_ZERO);
    unsigned short* W1b = (unsigned short*)(ws + B_W1B);
    unsigned short* W2b = (unsigned short*)(ws + B_W2B);

    float* out = (float*)d_out;
    // d_out scratch: h1 f16 [BT][256] in the first half of new_logits, xhf f16 [BT][256] in the second
    unsigned short* h1  = (unsigned short*)out;
    unsigned short* xhf = h1 + (size_t)BT * 256;

    hipMemsetAsync(dlog, 0, BT * sizeof(float), stream);
    hipMemsetAsync(sst, 0xFF, BT * sizeof(int), stream);
    hipMemsetAsync(sen, 0xFF, BT * sizeof(int), stream);
    hipMemsetAsync(uct, 0, sizeof(int), stream);
    hipMemsetAsync(zerobuf, 0, 256, stream);

    repack_kernel<<<1024, 256, 0, stream>>>(w1, w2, w3, W1T, W2T, v, W1b, W2b);
    xcast_kernel<<<BT * 256 / (8 * 256), 256, 0, stream>>>(x, xhf);
    conv1_mfma<<<dim3(BSZ * (T / 256), HDIM / 128), 256, 0, stream>>>(
        xhf, W1b, b1, zerobuf, h1);
    conv2_mfma<<<dim3(BSZ * (T / 256), HDIM / 128), 256, 0, stream>>>(
        h1, W2b, b2, v, zerobuf, dlog);
    boundary_kernel<<<BT / 256, 256, 0, stream>>>(dlog, padmask, b3, isb, uct, ul);
    recheck_kernel<<<2048, 256, 0, stream>>>(x, W1T, W2T, b1, b2, w3, b3, ul, uct, isb);
    scan_kernel<<<BSZ, 1024, 0, stream>>>(isb, padmask, sid, nv);
    segbounds_kernel<<<BT / 256, 256, 0, stream>>>(sid, padmask, sst, sen);
    pool_kernel<<<BT / 4, 256, 0, stream>>>(x, sst, sen, nv, out);
}